// Round 3
// baseline (337.424 us; speedup 1.0000x reference)
//
#include <hip/hip_runtime.h>
#include <hip/hip_bf16.h>
#include <cmath>

#define BB 4
#define SS 2048
#define DD 1024
#define BS (BB*SS)            // 8192 rows total
constexpr float EPS = 1e-6f;

typedef __attribute__((ext_vector_type(8))) short short8;
typedef __attribute__((ext_vector_type(4))) float floatx4;

// ---------------------------------------------------------------------------
// K0: convert Wk,Wq fp32 -> bf16 row-major. Wb = [Wk_bf (1024 rows) | Wq_bf]
// ---------------------------------------------------------------------------
__global__ __launch_bounds__(256)
void wconv_kernel(const float* __restrict__ Wq, const float* __restrict__ Wk,
                  __hip_bfloat16* __restrict__ Wb) {
    int idx = blockIdx.x * 256 + threadIdx.x;       // float4 index, 2*DD*DD/4 total
    const int half = DD * DD / 4;
    const float* src = (idx < half) ? Wk : Wq;
    int off = (idx < half) ? idx : idx - half;
    float4 v = ((const float4*)src)[off];
    union { ushort4 u; __hip_bfloat16 h[4]; } pk;
    pk.h[0] = __float2bfloat16(v.x);
    pk.h[1] = __float2bfloat16(v.y);
    pk.h[2] = __float2bfloat16(v.z);
    pk.h[3] = __float2bfloat16(v.w);
    ((ushort4*)Wb)[idx] = pk.u;
}

// ---------------------------------------------------------------------------
// K1: gemv: u[d]=Wq[d,:]·bk, v[e]=Wk[e,:]·bq, c=bq·bk  (one wave per output)
// ---------------------------------------------------------------------------
__global__ __launch_bounds__(256)
void gemv_kernel(const float* __restrict__ Wq, const float* __restrict__ Wk,
                 const float* __restrict__ bq, const float* __restrict__ bk,
                 float* __restrict__ u, float* __restrict__ v, float* __restrict__ cs) {
    int gid = blockIdx.x * 4 + (threadIdx.x >> 6);
    int lane = threadIdx.x & 63;
    if (gid > 2048) return;
    const float* row; const float* vec; float* outp;
    if (gid < 1024)      { row = Wq + (size_t)gid * DD;          vec = bk; outp = u + gid; }
    else if (gid < 2048) { row = Wk + (size_t)(gid - 1024) * DD; vec = bq; outp = v + (gid - 1024); }
    else                 { row = bq;                             vec = bk; outp = cs; }
    float s = 0.f;
    #pragma unroll
    for (int k = 0; k < 4; ++k) {
        float4 a = ((const float4*)row)[lane * 4 + k];
        float4 b = ((const float4*)vec)[lane * 4 + k];
        s += a.x * b.x + a.y * b.y + a.z * b.z + a.w * b.w;
    }
    #pragma unroll
    for (int off = 32; off; off >>= 1) s += __shfl_down(s, off);
    if (lane == 0) *outp = s;
}

// ---------------------------------------------------------------------------
// K2: LayerNorm -> bf16 x ; fused alpha[i]=x_i·u + c, beta[i]=x_i·v
// ---------------------------------------------------------------------------
__global__ __launch_bounds__(256)
void ln_kernel(const float* __restrict__ ctx, const float* __restrict__ gamma,
               const float* __restrict__ beta, const float* __restrict__ u,
               const float* __restrict__ v, const float* __restrict__ cs,
               __hip_bfloat16* __restrict__ xo, float* __restrict__ alpha,
               float* __restrict__ betav) {
    int row = blockIdx.x;
    int t = threadIdx.x;
    const float* r = ctx + (size_t)row * DD;
    float4 val = ((const float4*)r)[t];
    float s1 = val.x + val.y + val.z + val.w;
    float s2 = val.x*val.x + val.y*val.y + val.z*val.z + val.w*val.w;
    #pragma unroll
    for (int off = 32; off; off >>= 1) {
        s1 += __shfl_down(s1, off);
        s2 += __shfl_down(s2, off);
    }
    __shared__ float ls1[4], ls2[4];
    int wid = t >> 6, lane = t & 63;
    if (lane == 0) { ls1[wid] = s1; ls2[wid] = s2; }
    __syncthreads();
    if (t == 0) {
        float a = ls1[0] + ls1[1] + ls1[2] + ls1[3];
        float b = ls2[0] + ls2[1] + ls2[2] + ls2[3];
        float mean = a / DD;
        float var = (b - a * a / DD) / (DD - 1);
        ls1[0] = mean;
        ls2[0] = 1.0f / (sqrtf(var) + EPS);
    }
    __syncthreads();
    float mean = ls1[0], rstd = ls2[0];
    float4 g = ((const float4*)gamma)[t];
    float4 be = ((const float4*)beta)[t];
    float nx0 = g.x * (val.x - mean) * rstd + be.x;
    float nx1 = g.y * (val.y - mean) * rstd + be.y;
    float nx2 = g.z * (val.z - mean) * rstd + be.z;
    float nx3 = g.w * (val.w - mean) * rstd + be.w;
    union { ushort4 uu; __hip_bfloat16 h[4]; } pk;
    pk.h[0] = __float2bfloat16(nx0);
    pk.h[1] = __float2bfloat16(nx1);
    pk.h[2] = __float2bfloat16(nx2);
    pk.h[3] = __float2bfloat16(nx3);
    ((ushort4*)(xo + (size_t)row * DD))[t] = pk.uu;
    // fused alpha/beta dots
    float4 u4 = ((const float4*)u)[t];
    float4 v4 = ((const float4*)v)[t];
    float du = nx0 * u4.x + nx1 * u4.y + nx2 * u4.z + nx3 * u4.w;
    float dv = nx0 * v4.x + nx1 * v4.y + nx2 * v4.z + nx3 * v4.w;
    #pragma unroll
    for (int off = 32; off; off >>= 1) {
        du += __shfl_down(du, off);
        dv += __shfl_down(dv, off);
    }
    __syncthreads();
    if (lane == 0) { ls1[wid] = du; ls2[wid] = dv; }
    __syncthreads();
    if (t == 0) {
        alpha[row] = ls1[0] + ls1[1] + ls1[2] + ls1[3] + *cs;
        betav[row] = ls2[0] + ls2[1] + ls2[2] + ls2[3];
    }
}

// ---------------------------------------------------------------------------
// K3: MFMA GEMM  C[M x N] = A @ B^T  (A[M][1024], B[N][1024] bf16, C bf16)
// 128x128 block, 4 waves of 64x64, BK=32, mfma_f32_16x16x32_bf16
// Coalesced epilogue through LDS (stride 72 shorts).
// ---------------------------------------------------------------------------
#define TM 128
#define TN 128
#define TK 32
__global__ __launch_bounds__(256)
void gemm_mfma(const __hip_bfloat16* __restrict__ A,
               const __hip_bfloat16* __restrict__ B,
               __hip_bfloat16* __restrict__ C, int ldc) {
    __shared__ short smem[18432];            // 36 KB
    short* As = smem;                        // TM*TK = 4096 shorts
    short* Bs = smem + TM * TK;              // 4096 shorts
    int tid = threadIdx.x;
    int wave = tid >> 6;
    int lane = tid & 63;
    int wm = wave >> 1, wn = wave & 1;
    int q = lane >> 4, m16 = lane & 15;

    int srow = lane >> 2;
    int skoff = (lane & 3) * 8;
    const __hip_bfloat16* gA = A + ((size_t)blockIdx.x * TM + wave * 32 + srow) * DD + skoff;
    const __hip_bfloat16* gB = B + ((size_t)blockIdx.y * TN + wave * 32 + srow) * DD + skoff;
    short* lAbase = As + (wave * 32) * TK;   // wave-uniform
    short* lBbase = Bs + (wave * 32) * TK;

    floatx4 acc[4][4] = {};

    for (int k0 = 0; k0 < DD; k0 += TK) {
        __builtin_amdgcn_global_load_lds(
            (const __attribute__((address_space(1))) void*)(gA + k0),
            (__attribute__((address_space(3))) void*)(lAbase), 16, 0, 0);
        __builtin_amdgcn_global_load_lds(
            (const __attribute__((address_space(1))) void*)(gA + k0 + 16 * DD),
            (__attribute__((address_space(3))) void*)(lAbase + 16 * TK), 16, 0, 0);
        __builtin_amdgcn_global_load_lds(
            (const __attribute__((address_space(1))) void*)(gB + k0),
            (__attribute__((address_space(3))) void*)(lBbase), 16, 0, 0);
        __builtin_amdgcn_global_load_lds(
            (const __attribute__((address_space(1))) void*)(gB + k0 + 16 * DD),
            (__attribute__((address_space(3))) void*)(lBbase + 16 * TK), 16, 0, 0);
        __syncthreads();
        short8 af[4], bf[4];
        #pragma unroll
        for (int r = 0; r < 4; ++r)
            af[r] = *(const short8*)(As + (wm * 64 + r * 16 + m16) * TK + q * 8);
        #pragma unroll
        for (int c = 0; c < 4; ++c)
            bf[c] = *(const short8*)(Bs + (wn * 64 + c * 16 + m16) * TK + q * 8);
        #pragma unroll
        for (int r = 0; r < 4; ++r)
            #pragma unroll
            for (int c = 0; c < 4; ++c)
                acc[r][c] = __builtin_amdgcn_mfma_f32_16x16x32_bf16(af[r], bf[c], acc[r][c], 0, 0, 0);
        __syncthreads();
    }

    // epilogue: write wave's 64x64 tile into LDS (stride 72), coalesced store
    short* EP = smem + wave * 4608;          // 64 rows x 72 shorts
    #pragma unroll
    for (int r = 0; r < 4; ++r)
        #pragma unroll
        for (int c = 0; c < 4; ++c)
            #pragma unroll
            for (int e = 0; e < 4; ++e) {
                __hip_bfloat16 hv = __float2bfloat16(acc[r][c][e]);
                EP[(r * 16 + q * 4 + e) * 72 + c * 16 + m16] = *(short*)&hv;
            }
    int grow0 = blockIdx.x * TM + wm * 64;
    int gcol0 = blockIdx.y * TN + wn * 64;
    short* Cc = (short*)C;
    #pragma unroll
    for (int it = 0; it < 8; ++it) {
        int rl = it * 8 + (lane >> 3);
        int cg = (lane & 7) * 8;
        short8 vv = *(const short8*)(EP + rl * 72 + cg);
        *(short8*)(Cc + (size_t)(grow0 + rl) * ldc + gcol0 + cg) = vv;
    }
}

// ---------------------------------------------------------------------------
// K4: band scores s_sup/s_sub from z,x + rank-1 terms; 2-entry softmax
// ---------------------------------------------------------------------------
__global__ __launch_bounds__(256)
void band_kernel(const __hip_bfloat16* __restrict__ z, const __hip_bfloat16* __restrict__ x,
                 const int* __restrict__ eos, const float* __restrict__ alpha,
                 const float* __restrict__ betav, float* __restrict__ vsub,
                 float* __restrict__ vsup, float* __restrict__ wuni) {
    int gw = (blockIdx.x * blockDim.x + threadIdx.x) >> 6;  // row id 0..BS-1
    int lane = threadIdx.x & 63;
    int i = gw & (SS - 1);
    float zv[16];
    {
        const ushort4* p = (const ushort4*)(z + (size_t)gw * DD + lane * 16);
        #pragma unroll
        for (int m = 0; m < 4; ++m) {
            union { ushort4 u; __hip_bfloat16 h[4]; } cv; cv.u = p[m];
            #pragma unroll
            for (int r = 0; r < 4; ++r) zv[m * 4 + r] = __bfloat162float(cv.h[r]);
        }
    }
    float ssup = 0.f, ssub = 0.f;
    if (i < SS - 1) {
        const ushort4* p = (const ushort4*)(x + (size_t)(gw + 1) * DD + lane * 16);
        #pragma unroll
        for (int m = 0; m < 4; ++m) {
            union { ushort4 u; __hip_bfloat16 h[4]; } cv; cv.u = p[m];
            #pragma unroll
            for (int r = 0; r < 4; ++r) ssup += zv[m * 4 + r] * __bfloat162float(cv.h[r]);
        }
    }
    if (i > 0) {
        const ushort4* p = (const ushort4*)(x + (size_t)(gw - 1) * DD + lane * 16);
        #pragma unroll
        for (int m = 0; m < 4; ++m) {
            union { ushort4 u; __hip_bfloat16 h[4]; } cv; cv.u = p[m];
            #pragma unroll
            for (int r = 0; r < 4; ++r) ssub += zv[m * 4 + r] * __bfloat162float(cv.h[r]);
        }
    }
    #pragma unroll
    for (int off = 32; off; off >>= 1) {
        ssup += __shfl_down(ssup, off);
        ssub += __shfl_down(ssub, off);
    }
    if (lane == 0) {
        float a = alpha[gw];
        if (i < SS - 1) ssup = (ssup + a + betav[gw + 1]) * (1.0f / DD);
        if (i > 0)      ssub = (ssub + a + betav[gw - 1]) * (1.0f / DD);
        bool msub = (i > 0) && (eos[(size_t)gw * SS + (i - 1)] != 0);
        bool msup = (i < SS - 1) && (eos[(size_t)gw * SS + (i + 1)] != 0);
        float vs, vp, w;
        if (msub && msup) {
            float mx = fmaxf(ssub, ssup);
            float e1 = expf(ssub - mx), e2 = expf(ssup - mx);
            float inv = 1.0f / (e1 + e2);
            vs = e1 * inv; vp = e2 * inv; w = 0.f;
        } else if (msub) { vs = 1.f; vp = 0.f; w = 0.f; }
        else if (msup)   { vs = 0.f; vp = 1.f; w = 0.f; }
        else             { vs = vp = w = 1.0f / SS; }
        vsub[gw] = vs; vsup[gw] = vp; wuni[gw] = w;
    }
}

// ---------------------------------------------------------------------------
// K5: per batch, Lc[i] = sum_{t<i} log(na3[t,t+1] + 1e-9)  (double precision)
// ---------------------------------------------------------------------------
__global__ __launch_bounds__(256)
void scan_kernel(const float* __restrict__ prior, const float* __restrict__ vsub,
                 const float* __restrict__ vsup, double* __restrict__ Lc) {
    int b = blockIdx.x;
    int t = threadIdx.x;
    double loc[8];
    double s = 0.0;
    #pragma unroll
    for (int k = 0; k < 8; ++k) {
        int tt = t * 8 + k;
        double Lv = 0.0;
        if (tt < SS - 1) {
            float pr = prior[((size_t)(b * SS + tt)) * SS + tt + 1];
            float na2 = sqrtf(vsup[b * SS + tt] * vsub[b * SS + tt + 1] + 1e-9f);
            float P = pr + (1.f - pr) * na2;
            Lv = log((double)P + 1e-9);
        }
        loc[k] = Lv; s += Lv;
    }
    __shared__ double sa[256], sb[256];
    sa[t] = s;
    __syncthreads();
    double* src = sa; double* dst = sb;
    for (int off = 1; off < 256; off <<= 1) {
        double v = src[t];
        if (t >= off) v += src[t - off];
        __syncthreads();
        dst[t] = v;
        __syncthreads();
        double* tmp = src; src = dst; dst = tmp;
    }
    double run = (t == 0) ? 0.0 : src[t - 1];
    #pragma unroll
    for (int k = 0; k < 8; ++k) {
        int idx = t * 8 + k;
        Lc[b * SS + idx] = run;   // exclusive prefix
        run += loc[k];
    }
}

// ---------------------------------------------------------------------------
// K6: fused output pass: na3 (dense) and g_attn, 4 cols per thread
// ---------------------------------------------------------------------------
__global__ __launch_bounds__(256)
void out_kernel(const float* __restrict__ prior, const float* __restrict__ vsub,
                const float* __restrict__ vsup, const float* __restrict__ wuni,
                const double* __restrict__ Lc, float* __restrict__ out_g,
                float* __restrict__ out_na) {
    size_t gid = (size_t)blockIdx.x * 256 + threadIdx.x;   // 0 .. B*S*S/4-1
    int jt = (int)(gid & 511);
    int row = (int)(gid >> 9);          // b*S + i
    int i = row & (SS - 1);
    int b = row >> 11;
    int j0 = jt * 4;
    size_t base = (size_t)row * SS + j0;
    float4 pr4 = *(const float4*)(prior + base);
    float4 wj4 = *(const float4*)(wuni + b * SS + j0);
    float pra[4] = {pr4.x, pr4.y, pr4.z, pr4.w};
    float wja[4] = {wj4.x, wj4.y, wj4.z, wj4.w};
    float wi = wuni[row];
    double Lci = Lc[row];
    const double* Lcb = Lc + b * SS;
    float nav[4], gv[4];
    #pragma unroll
    for (int c = 0; c < 4; ++c) {
        int j = j0 + c;
        float prod;
        if (j == i - 1)      prod = vsub[row] * vsup[row - 1];
        else if (j == i + 1) prod = vsup[row] * vsub[row + 1];
        else if (j == i)     prod = wi * wi;
        else                 prod = wi * wja[c];
        float na2 = sqrtf(prod + 1e-9f);
        float p = pra[c];
        float na3 = p + (1.f - p) * na2;
        nav[c] = na3;
        if (j == i) {
            gv[c] = na3;
        } else {
            double d = (j > i) ? (Lcb[j] - Lci) : (Lci - Lcb[j]);
            gv[c] = expf((float)d) + 1e-9f;
        }
    }
    *(float4*)(out_g + base) = make_float4(gv[0], gv[1], gv[2], gv[3]);
    *(float4*)(out_na + base) = make_float4(nav[0], nav[1], nav[2], nav[3]);
}

// ---------------------------------------------------------------------------
extern "C" void kernel_launch(void* const* d_in, const int* in_sizes, int n_in,
                              void* d_out, int out_size, void* d_ws, size_t ws_size,
                              hipStream_t stream) {
    const float* ctx   = (const float*)d_in[0];
    const int*   eos   = (const int*)d_in[1];
    const float* prior = (const float*)d_in[2];
    const float* Wq    = (const float*)d_in[3];
    const float* bq    = (const float*)d_in[4];
    const float* Wk    = (const float*)d_in[5];
    const float* bk    = (const float*)d_in[6];
    const float* gamma = (const float*)d_in[7];
    const float* beta  = (const float*)d_in[8];

    float* out_g  = (float*)d_out;
    float* out_na = out_g + (size_t)BB * SS * SS;

    char* ws = (char*)d_ws;
    size_t o = 0;
    __hip_bfloat16* x  = (__hip_bfloat16*)(ws + o); o += (size_t)BS * DD * 2;   // 16 MiB
    __hip_bfloat16* z  = (__hip_bfloat16*)(ws + o); o += (size_t)BS * DD * 2;   // 16 MiB
    __hip_bfloat16* Wb = (__hip_bfloat16*)(ws + o); o += (size_t)2 * DD * DD * 2; // 4 MiB [Wk|Wq]
    __hip_bfloat16* Mt = (__hip_bfloat16*)(ws + o); o += (size_t)DD * DD * 2;   // 2 MiB
    double* Lc   = (double*)(ws + o); o += (size_t)BS * 8;                      // 64 KiB
    float* u     = (float*)(ws + o);  o += DD * 4;
    float* v     = (float*)(ws + o);  o += DD * 4;
    float* cs    = (float*)(ws + o);  o += 64;
    float* alpha = (float*)(ws + o);  o += (size_t)BS * 4;
    float* betav = (float*)(ws + o);  o += (size_t)BS * 4;
    float* vsub  = (float*)(ws + o);  o += (size_t)BS * 4;
    float* vsup  = (float*)(ws + o);  o += (size_t)BS * 4;
    float* wuni  = (float*)(ws + o);  o += (size_t)BS * 4;

    __hip_bfloat16* Wk_bf = Wb;
    __hip_bfloat16* Wq_bf = Wb + (size_t)DD * DD;

    wconv_kernel<<<(2 * DD * DD / 4) / 256, 256, 0, stream>>>(Wq, Wk, Wb);
    gemv_kernel<<<513, 256, 0, stream>>>(Wq, Wk, bq, bk, u, v, cs);
    ln_kernel<<<BS, 256, 0, stream>>>(ctx, gamma, beta, u, v, cs, x, alpha, betav);

    // Mt[j,d] = sum_e Wk[j,e] Wq[d,e]   (1024x1024)
    dim3 g1(DD / TM, DD / TN);
    gemm_mfma<<<g1, 256, 0, stream>>>(Wk_bf, Wq_bf, Mt, DD);

    // z[i,j] = sum_d x[i,d] Mt[j,d]     (8192x1024)
    dim3 g2(BS / TM, DD / TN);
    gemm_mfma<<<g2, 256, 0, stream>>>(x, Mt, z, DD);

    band_kernel<<<BS / 4, 256, 0, stream>>>(z, x, eos, alpha, betav, vsub, vsup, wuni);

    scan_kernel<<<BB, 256, 0, stream>>>(prior, vsub, vsup, Lc);

    size_t total = (size_t)BB * SS * SS / 4;
    out_kernel<<<(int)(total / 256), 256, 0, stream>>>(prior, vsub, vsup, wuni, Lc,
                                                       out_g, out_na);
}

// Round 4
// 326.744 us; speedup vs baseline: 1.0327x; 1.0327x over previous
//
#include <hip/hip_runtime.h>
#include <hip/hip_bf16.h>
#include <cmath>

#define BB 4
#define SS 2048
#define DD 1024
#define BS (BB*SS)            // 8192 rows total
constexpr float EPS = 1e-6f;

typedef __attribute__((ext_vector_type(8))) short short8;
typedef __attribute__((ext_vector_type(4))) float floatx4;

__device__ inline float bf2f(unsigned short u) {
    unsigned v = ((unsigned)u) << 16;
    float f; __builtin_memcpy(&f, &v, 4);
    return f;
}

// ---------------------------------------------------------------------------
// K0 (prep): blocks [0,2048): convert Wk,Wq fp32->bf16  Wb=[Wk_bf|Wq_bf]
//            blocks [2048,2561): gemv u=Wq·bk, v=Wk·bq, cs=bq·bk
//            blocks [2561,2577): zero sacc (2*BS floats)
// ---------------------------------------------------------------------------
__global__ __launch_bounds__(256)
void prep_kernel(const float* __restrict__ Wq, const float* __restrict__ Wk,
                 const float* __restrict__ bq, const float* __restrict__ bk,
                 __hip_bfloat16* __restrict__ Wb, float* __restrict__ u,
                 float* __restrict__ v, float* __restrict__ cs,
                 float* __restrict__ sacc) {
    int blk = blockIdx.x;
    if (blk < 2048) {
        int idx = blk * 256 + threadIdx.x;          // float4 index over 2*DD*DD/4
        const int half = DD * DD / 4;
        const float* src = (idx < half) ? Wk : Wq;
        int off = (idx < half) ? idx : idx - half;
        float4 val = ((const float4*)src)[off];
        union { ushort4 uu; __hip_bfloat16 h[4]; } pk;
        pk.h[0] = __float2bfloat16(val.x);
        pk.h[1] = __float2bfloat16(val.y);
        pk.h[2] = __float2bfloat16(val.z);
        pk.h[3] = __float2bfloat16(val.w);
        ((ushort4*)Wb)[idx] = pk.uu;
    } else if (blk < 2561) {
        int gid = (blk - 2048) * 4 + (threadIdx.x >> 6);
        int lane = threadIdx.x & 63;
        if (gid > 2048) return;
        const float* row; const float* vec; float* outp;
        if (gid < 1024)      { row = Wq + (size_t)gid * DD;          vec = bk; outp = u + gid; }
        else if (gid < 2048) { row = Wk + (size_t)(gid - 1024) * DD; vec = bq; outp = v + (gid - 1024); }
        else                 { row = bq;                             vec = bk; outp = cs; }
        float s = 0.f;
        #pragma unroll
        for (int k = 0; k < 4; ++k) {
            float4 a = ((const float4*)row)[lane * 4 + k];
            float4 b = ((const float4*)vec)[lane * 4 + k];
            s += a.x * b.x + a.y * b.y + a.z * b.z + a.w * b.w;
        }
        #pragma unroll
        for (int off = 32; off; off >>= 1) s += __shfl_down(s, off);
        if (lane == 0) *outp = s;
    } else {
        int idx = (blk - 2561) * 1024 + threadIdx.x * 4;   // 16 blocks * 1024 = 16384
        *(float4*)(sacc + idx) = make_float4(0.f, 0.f, 0.f, 0.f);
    }
}

// ---------------------------------------------------------------------------
// K1: LayerNorm -> bf16 x ; fused alpha[i]=x_i·u + c, beta[i]=x_i·v
// ---------------------------------------------------------------------------
__global__ __launch_bounds__(256)
void ln_kernel(const float* __restrict__ ctx, const float* __restrict__ gamma,
               const float* __restrict__ beta, const float* __restrict__ u,
               const float* __restrict__ v, const float* __restrict__ cs,
               __hip_bfloat16* __restrict__ xo, float* __restrict__ alpha,
               float* __restrict__ betav) {
    int row = blockIdx.x;
    int t = threadIdx.x;
    const float* r = ctx + (size_t)row * DD;
    float4 val = ((const float4*)r)[t];
    float s1 = val.x + val.y + val.z + val.w;
    float s2 = val.x*val.x + val.y*val.y + val.z*val.z + val.w*val.w;
    #pragma unroll
    for (int off = 32; off; off >>= 1) {
        s1 += __shfl_down(s1, off);
        s2 += __shfl_down(s2, off);
    }
    __shared__ float ls1[4], ls2[4];
    int wid = t >> 6, lane = t & 63;
    if (lane == 0) { ls1[wid] = s1; ls2[wid] = s2; }
    __syncthreads();
    if (t == 0) {
        float a = ls1[0] + ls1[1] + ls1[2] + ls1[3];
        float b = ls2[0] + ls2[1] + ls2[2] + ls2[3];
        float mean = a / DD;
        float var = (b - a * a / DD) / (DD - 1);
        ls1[0] = mean;
        ls2[0] = 1.0f / (sqrtf(var) + EPS);
    }
    __syncthreads();
    float mean = ls1[0], rstd = ls2[0];
    float4 g = ((const float4*)gamma)[t];
    float4 be = ((const float4*)beta)[t];
    float nx0 = g.x * (val.x - mean) * rstd + be.x;
    float nx1 = g.y * (val.y - mean) * rstd + be.y;
    float nx2 = g.z * (val.z - mean) * rstd + be.z;
    float nx3 = g.w * (val.w - mean) * rstd + be.w;
    union { ushort4 uu; __hip_bfloat16 h[4]; } pk;
    pk.h[0] = __float2bfloat16(nx0);
    pk.h[1] = __float2bfloat16(nx1);
    pk.h[2] = __float2bfloat16(nx2);
    pk.h[3] = __float2bfloat16(nx3);
    ((ushort4*)(xo + (size_t)row * DD))[t] = pk.uu;
    float4 u4 = ((const float4*)u)[t];
    float4 v4 = ((const float4*)v)[t];
    float du = nx0 * u4.x + nx1 * u4.y + nx2 * u4.z + nx3 * u4.w;
    float dv = nx0 * v4.x + nx1 * v4.y + nx2 * v4.z + nx3 * v4.w;
    #pragma unroll
    for (int off = 32; off; off >>= 1) {
        du += __shfl_down(du, off);
        dv += __shfl_down(dv, off);
    }
    __syncthreads();
    if (lane == 0) { ls1[wid] = du; ls2[wid] = dv; }
    __syncthreads();
    if (t == 0) {
        alpha[row] = ls1[0] + ls1[1] + ls1[2] + ls1[3] + *cs;
        betav[row] = ls2[0] + ls2[1] + ls2[2] + ls2[3];
    }
}

// ---------------------------------------------------------------------------
// K2: 64x64-tile MFMA GEMM for Mt = Wk @ Wq^T  (grid 16x16 = 256 blocks)
// 4 waves, each 16 rows x 64 cols; BK=64
// ---------------------------------------------------------------------------
__global__ __launch_bounds__(256)
void gemm64_mfma(const __hip_bfloat16* __restrict__ A,
                 const __hip_bfloat16* __restrict__ B,
                 __hip_bfloat16* __restrict__ C, int ldc) {
    __shared__ short As[64 * 64];
    __shared__ short Bs[64 * 64];
    int tid = threadIdx.x;
    int wave = tid >> 6;
    int lane = tid & 63;
    int q = lane >> 4, m16 = lane & 15;
    int srow = lane >> 3;          // 0..7
    int skoff = (lane & 7) * 8;

    const __hip_bfloat16* gA = A + ((size_t)blockIdx.x * 64 + wave * 16 + srow) * DD + skoff;
    const __hip_bfloat16* gB = B + ((size_t)blockIdx.y * 64 + wave * 16 + srow) * DD + skoff;
    short* lA0 = As + (wave * 16) * 64;
    short* lA1 = As + (wave * 16 + 8) * 64;
    short* lB0 = Bs + (wave * 16) * 64;
    short* lB1 = Bs + (wave * 16 + 8) * 64;

    floatx4 acc[4] = {};
    for (int k0 = 0; k0 < DD; k0 += 64) {
        __builtin_amdgcn_global_load_lds(
            (const __attribute__((address_space(1))) void*)(gA + k0),
            (__attribute__((address_space(3))) void*)(lA0), 16, 0, 0);
        __builtin_amdgcn_global_load_lds(
            (const __attribute__((address_space(1))) void*)(gA + k0 + 8 * DD),
            (__attribute__((address_space(3))) void*)(lA1), 16, 0, 0);
        __builtin_amdgcn_global_load_lds(
            (const __attribute__((address_space(1))) void*)(gB + k0),
            (__attribute__((address_space(3))) void*)(lB0), 16, 0, 0);
        __builtin_amdgcn_global_load_lds(
            (const __attribute__((address_space(1))) void*)(gB + k0 + 8 * DD),
            (__attribute__((address_space(3))) void*)(lB1), 16, 0, 0);
        __syncthreads();
        #pragma unroll
        for (int h = 0; h < 2; ++h) {
            short8 af = *(const short8*)(As + (wave * 16 + m16) * 64 + h * 32 + q * 8);
            #pragma unroll
            for (int c = 0; c < 4; ++c) {
                short8 bf_ = *(const short8*)(Bs + (c * 16 + m16) * 64 + h * 32 + q * 8);
                acc[c] = __builtin_amdgcn_mfma_f32_16x16x32_bf16(af, bf_, acc[c], 0, 0, 0);
            }
        }
        __syncthreads();
    }
    #pragma unroll
    for (int c = 0; c < 4; ++c) {
        int gcol = blockIdx.y * 64 + c * 16 + m16;
        #pragma unroll
        for (int e = 0; e < 4; ++e) {
            int grow = blockIdx.x * 64 + wave * 16 + q * 4 + e;
            C[(size_t)grow * ldc + gcol] = __float2bfloat16(acc[c][e]);
        }
    }
}

// ---------------------------------------------------------------------------
// K3: MFMA GEMM z = x @ Mt^T with FUSED band epilogue (z never stored):
// per wave, stage 64x64 z-tile to LDS (bf16), dot z rows against x[row±1]
// col-slices, atomicAdd partials into sacc[0..BS) (sup) and sacc[BS..2BS) (sub)
// ---------------------------------------------------------------------------
#define TM 128
#define TN 128
#define TK 32
__global__ __launch_bounds__(256)
void gemm2_fused(const __hip_bfloat16* __restrict__ A,    // x
                 const __hip_bfloat16* __restrict__ B,    // Mt
                 float* __restrict__ sacc) {
    __shared__ short smem[18432];            // 36 KB
    short* As = smem;
    short* Bs = smem + TM * TK;
    int tid = threadIdx.x;
    int wave = tid >> 6;
    int lane = tid & 63;
    int wm = wave >> 1, wn = wave & 1;
    int q = lane >> 4, m16 = lane & 15;

    int srow = lane >> 2;
    int skoff = (lane & 3) * 8;
    const __hip_bfloat16* gA = A + ((size_t)blockIdx.x * TM + wave * 32 + srow) * DD + skoff;
    const __hip_bfloat16* gB = B + ((size_t)blockIdx.y * TN + wave * 32 + srow) * DD + skoff;
    short* lAbase = As + (wave * 32) * TK;
    short* lBbase = Bs + (wave * 32) * TK;

    floatx4 acc[4][4] = {};

    for (int k0 = 0; k0 < DD; k0 += TK) {
        __builtin_amdgcn_global_load_lds(
            (const __attribute__((address_space(1))) void*)(gA + k0),
            (__attribute__((address_space(3))) void*)(lAbase), 16, 0, 0);
        __builtin_amdgcn_global_load_lds(
            (const __attribute__((address_space(1))) void*)(gA + k0 + 16 * DD),
            (__attribute__((address_space(3))) void*)(lAbase + 16 * TK), 16, 0, 0);
        __builtin_amdgcn_global_load_lds(
            (const __attribute__((address_space(1))) void*)(gB + k0),
            (__attribute__((address_space(3))) void*)(lBbase), 16, 0, 0);
        __builtin_amdgcn_global_load_lds(
            (const __attribute__((address_space(1))) void*)(gB + k0 + 16 * DD),
            (__attribute__((address_space(3))) void*)(lBbase + 16 * TK), 16, 0, 0);
        __syncthreads();
        short8 af[4], bf_[4];
        #pragma unroll
        for (int r = 0; r < 4; ++r)
            af[r] = *(const short8*)(As + (wm * 64 + r * 16 + m16) * TK + q * 8);
        #pragma unroll
        for (int c = 0; c < 4; ++c)
            bf_[c] = *(const short8*)(Bs + (wn * 64 + c * 16 + m16) * TK + q * 8);
        #pragma unroll
        for (int r = 0; r < 4; ++r)
            #pragma unroll
            for (int c = 0; c < 4; ++c)
                acc[r][c] = __builtin_amdgcn_mfma_f32_16x16x32_bf16(af[r], bf_[c], acc[r][c], 0, 0, 0);
        __syncthreads();
    }

    // stage wave's 64x64 z-tile (bf16) into LDS, stride 72 shorts
    short* EP = smem + wave * 4608;
    #pragma unroll
    for (int r = 0; r < 4; ++r)
        #pragma unroll
        for (int c = 0; c < 4; ++c)
            #pragma unroll
            for (int e = 0; e < 4; ++e) {
                __hip_bfloat16 hv = __float2bfloat16(acc[r][c][e]);
                EP[(r * 16 + q * 4 + e) * 72 + c * 16 + m16] = *(short*)&hv;
            }

    // per-lane: dot z row (64 cols) with x[row+1] and x[row-1] col-slices
    int rl = lane;
    int growZ = blockIdx.x * TM + wm * 64 + rl;
    int gcol0 = blockIdx.y * TN + wn * 64;
    float zf[64];
    #pragma unroll
    for (int c8 = 0; c8 < 8; ++c8) {
        short8 zz = *(const short8*)(EP + rl * 72 + c8 * 8);
        #pragma unroll
        for (int e = 0; e < 8; ++e) zf[c8 * 8 + e] = bf2f((unsigned short)zz[e]);
    }
    if (growZ + 1 < BS) {
        const short8* px = (const short8*)(A + (size_t)(growZ + 1) * DD + gcol0);
        float sup = 0.f;
        #pragma unroll
        for (int c8 = 0; c8 < 8; ++c8) {
            short8 xx = px[c8];
            #pragma unroll
            for (int e = 0; e < 8; ++e) sup += zf[c8 * 8 + e] * bf2f((unsigned short)xx[e]);
        }
        atomicAdd(&sacc[growZ], sup);
    }
    if (growZ >= 1) {
        const short8* px = (const short8*)(A + (size_t)(growZ - 1) * DD + gcol0);
        float sub = 0.f;
        #pragma unroll
        for (int c8 = 0; c8 < 8; ++c8) {
            short8 xx = px[c8];
            #pragma unroll
            for (int e = 0; e < 8; ++e) sub += zf[c8 * 8 + e] * bf2f((unsigned short)xx[e]);
        }
        atomicAdd(&sacc[BS + growZ], sub);
    }
}

// ---------------------------------------------------------------------------
// K4: per-row 2-entry softmax from accumulated band scores
// ---------------------------------------------------------------------------
__global__ __launch_bounds__(256)
void softmax_kernel(const float* __restrict__ sacc, const int* __restrict__ eos,
                    const float* __restrict__ alpha, const float* __restrict__ betav,
                    float* __restrict__ vsub, float* __restrict__ vsup,
                    float* __restrict__ wuni) {
    int gw = blockIdx.x * 256 + threadIdx.x;   // 0..BS-1
    int i = gw & (SS - 1);
    float a = alpha[gw];
    float ssup = 0.f, ssub = 0.f;
    if (i < SS - 1) ssup = (sacc[gw] + a + betav[gw + 1]) * (1.0f / DD);
    if (i > 0)      ssub = (sacc[BS + gw] + a + betav[gw - 1]) * (1.0f / DD);
    bool msub = (i > 0) && (eos[(size_t)gw * SS + (i - 1)] != 0);
    bool msup = (i < SS - 1) && (eos[(size_t)gw * SS + (i + 1)] != 0);
    float vs, vp, w;
    if (msub && msup) {
        float mx = fmaxf(ssub, ssup);
        float e1 = expf(ssub - mx), e2 = expf(ssup - mx);
        float inv = 1.0f / (e1 + e2);
        vs = e1 * inv; vp = e2 * inv; w = 0.f;
    } else if (msub) { vs = 1.f; vp = 0.f; w = 0.f; }
    else if (msup)   { vs = 0.f; vp = 1.f; w = 0.f; }
    else             { vs = vp = w = 1.0f / SS; }
    vsub[gw] = vs; vsup[gw] = vp; wuni[gw] = w;
}

// ---------------------------------------------------------------------------
// K5: per batch, Lc[i] = sum_{t<i} log(na3[t,t+1] + 1e-9)  (double precision)
// ---------------------------------------------------------------------------
__global__ __launch_bounds__(256)
void scan_kernel(const float* __restrict__ prior, const float* __restrict__ vsub,
                 const float* __restrict__ vsup, double* __restrict__ Lc) {
    int b = blockIdx.x;
    int t = threadIdx.x;
    double loc[8];
    double s = 0.0;
    #pragma unroll
    for (int k = 0; k < 8; ++k) {
        int tt = t * 8 + k;
        double Lv = 0.0;
        if (tt < SS - 1) {
            float pr = prior[((size_t)(b * SS + tt)) * SS + tt + 1];
            float na2 = sqrtf(vsup[b * SS + tt] * vsub[b * SS + tt + 1] + 1e-9f);
            float P = pr + (1.f - pr) * na2;
            Lv = log((double)P + 1e-9);
        }
        loc[k] = Lv; s += Lv;
    }
    __shared__ double sa[256], sb[256];
    sa[t] = s;
    __syncthreads();
    double* src = sa; double* dst = sb;
    for (int off = 1; off < 256; off <<= 1) {
        double v = src[t];
        if (t >= off) v += src[t - off];
        __syncthreads();
        dst[t] = v;
        __syncthreads();
        double* tmp = src; src = dst; dst = tmp;
    }
    double run = (t == 0) ? 0.0 : src[t - 1];
    #pragma unroll
    for (int k = 0; k < 8; ++k) {
        int idx = t * 8 + k;
        Lc[b * SS + idx] = run;   // exclusive prefix
        run += loc[k];
    }
}

// ---------------------------------------------------------------------------
// K6: fused output pass: na3 (dense) and g_attn, 4 cols per thread
// ---------------------------------------------------------------------------
__global__ __launch_bounds__(256)
void out_kernel(const float* __restrict__ prior, const float* __restrict__ vsub,
                const float* __restrict__ vsup, const float* __restrict__ wuni,
                const double* __restrict__ Lc, float* __restrict__ out_g,
                float* __restrict__ out_na) {
    size_t gid = (size_t)blockIdx.x * 256 + threadIdx.x;   // 0 .. B*S*S/4-1
    int jt = (int)(gid & 511);
    int row = (int)(gid >> 9);          // b*S + i
    int i = row & (SS - 1);
    int b = row >> 11;
    int j0 = jt * 4;
    size_t base = (size_t)row * SS + j0;
    float4 pr4 = *(const float4*)(prior + base);
    float4 wj4 = *(const float4*)(wuni + b * SS + j0);
    float pra[4] = {pr4.x, pr4.y, pr4.z, pr4.w};
    float wja[4] = {wj4.x, wj4.y, wj4.z, wj4.w};
    float wi = wuni[row];
    double Lci = Lc[row];
    const double* Lcb = Lc + b * SS;
    float nav[4], gv[4];
    #pragma unroll
    for (int c = 0; c < 4; ++c) {
        int j = j0 + c;
        float prod;
        if (j == i - 1)      prod = vsub[row] * vsup[row - 1];
        else if (j == i + 1) prod = vsup[row] * vsub[row + 1];
        else if (j == i)     prod = wi * wi;
        else                 prod = wi * wja[c];
        float na2 = sqrtf(prod + 1e-9f);
        float p = pra[c];
        float na3 = p + (1.f - p) * na2;
        nav[c] = na3;
        if (j == i) {
            gv[c] = na3;
        } else {
            double d = (j > i) ? (Lcb[j] - Lci) : (Lci - Lcb[j]);
            gv[c] = expf((float)d) + 1e-9f;
        }
    }
    *(float4*)(out_g + base) = make_float4(gv[0], gv[1], gv[2], gv[3]);
    *(float4*)(out_na + base) = make_float4(nav[0], nav[1], nav[2], nav[3]);
}

// ---------------------------------------------------------------------------
extern "C" void kernel_launch(void* const* d_in, const int* in_sizes, int n_in,
                              void* d_out, int out_size, void* d_ws, size_t ws_size,
                              hipStream_t stream) {
    const float* ctx   = (const float*)d_in[0];
    const int*   eos   = (const int*)d_in[1];
    const float* prior = (const float*)d_in[2];
    const float* Wq    = (const float*)d_in[3];
    const float* bq    = (const float*)d_in[4];
    const float* Wk    = (const float*)d_in[5];
    const float* bk    = (const float*)d_in[6];
    const float* gamma = (const float*)d_in[7];
    const float* beta  = (const float*)d_in[8];

    float* out_g  = (float*)d_out;
    float* out_na = out_g + (size_t)BB * SS * SS;

    char* ws = (char*)d_ws;
    size_t o = 0;
    __hip_bfloat16* x  = (__hip_bfloat16*)(ws + o); o += (size_t)BS * DD * 2;     // 16 MiB
    __hip_bfloat16* Wb = (__hip_bfloat16*)(ws + o); o += (size_t)2 * DD * DD * 2; // 4 MiB [Wk|Wq]
    __hip_bfloat16* Mt = (__hip_bfloat16*)(ws + o); o += (size_t)DD * DD * 2;     // 2 MiB
    double* Lc   = (double*)(ws + o); o += (size_t)BS * 8;                        // 64 KiB
    float* u     = (float*)(ws + o);  o += DD * 4;
    float* v     = (float*)(ws + o);  o += DD * 4;
    float* cs    = (float*)(ws + o);  o += 64;
    float* alpha = (float*)(ws + o);  o += (size_t)BS * 4;
    float* betav = (float*)(ws + o);  o += (size_t)BS * 4;
    float* vsub  = (float*)(ws + o);  o += (size_t)BS * 4;
    float* vsup  = (float*)(ws + o);  o += (size_t)BS * 4;
    float* wuni  = (float*)(ws + o);  o += (size_t)BS * 4;
    float* sacc  = (float*)(ws + o);  o += (size_t)2 * BS * 4;                    // 64 KiB

    __hip_bfloat16* Wk_bf = Wb;
    __hip_bfloat16* Wq_bf = Wb + (size_t)DD * DD;

    prep_kernel<<<2577, 256, 0, stream>>>(Wq, Wk, bq, bk, Wb, u, v, cs, sacc);
    ln_kernel<<<BS, 256, 0, stream>>>(ctx, gamma, beta, u, v, cs, x, alpha, betav);

    // Mt[j,d] = sum_e Wk[j,e] Wq[d,e]   (1024x1024), 256 blocks
    dim3 g1(DD / 64, DD / 64);
    gemm64_mfma<<<g1, 256, 0, stream>>>(Wk_bf, Wq_bf, Mt, DD);

    // z = x @ Mt^T with fused band dot -> sacc
    dim3 g2(BS / TM, DD / TN);
    gemm2_fused<<<g2, 256, 0, stream>>>(x, Mt, sacc);

    softmax_kernel<<<BS / 256, 256, 0, stream>>>(sacc, eos, alpha, betav, vsub, vsup, wuni);

    scan_kernel<<<BB, 256, 0, stream>>>(prior, vsub, vsup, Lc);

    size_t total = (size_t)BB * SS * SS / 4;
    out_kernel<<<(int)(total / 256), 256, 0, stream>>>(prior, vsub, vsup, wuni, Lc,
                                                       out_g, out_na);
}